// Round 10
// baseline (137.633 us; speedup 1.0000x reference)
//
#include <hip/hip_runtime.h>
#include <stdint.h>

#define B_  4096
#define F_  512
#define T_  2048
#define D_  4
#define M_  (T_ * D_)   // 8192 GEMM-M (trees*dims)
#define KC_ (F_ / 8)    // 64 16-byte k-chunks per row
#define TAU 0.2018004745467103f

typedef __attribute__((ext_vector_type(8)))  short bf16x8;
typedef __attribute__((ext_vector_type(16))) float f32x16;

static __device__ __forceinline__ unsigned short f2bf(float f) {
  union { float f; uint32_t u; } v; v.f = f;
  uint32_t r = v.u + 0x7fffu + ((v.u >> 16) & 1u);  // RNE
  return (unsigned short)(r >> 16);
}
static __device__ __forceinline__ uint32_t pk2(float a, float b) {
  return ((uint32_t)f2bf(b) << 16) | f2bf(a);
}

// ---------------------------------------------------------------------------
// Prep v2 (verified round 5): fully-coalesced global IO via LDS transpose.
// ---------------------------------------------------------------------------
__global__ __launch_bounds__(256) void prep(
    const float* __restrict__ x, const float* __restrict__ logits,
    unsigned short* __restrict__ xbF, unsigned short* __restrict__ wbF) {
  __shared__ __align__(16) char sm[16384];
  const int tid = threadIdx.x;
  if (blockIdx.x < 256) {
    const int r0 = blockIdx.x * 16;
    const float4* x4 = (const float4*)x;
    #pragma unroll
    for (int p = 0; p < 8; ++p) {
      int idx = p * 256 + tid;
      int row = idx >> 7, col4 = idx & 127;
      int kc = col4 >> 1, half = col4 & 1;
      float4 f = x4[(size_t)(r0 + row) * 128 + col4];
      uint2 u = make_uint2(pk2(f.x, f.y), pk2(f.z, f.w));
      *(uint2*)(sm + (kc * 16 + (row ^ (kc & 15))) * 16 + half * 8) = u;
    }
    __syncthreads();
    const int w = tid >> 6, l = tid & 63;
    #pragma unroll
    for (int i = 0; i < 4; ++i) {
      int kc = w * 16 + i * 4 + (l >> 4);
      int slot = l & 15;
      int row = slot ^ (kc & 15);
      bf16x8 v = *(const bf16x8*)(sm + (kc * 16 + slot) * 16);
      *(bf16x8*)(xbF + ((size_t)kc * B_ + r0 + row) * 8) = v;
    }
  } else {
    const int m0r = (blockIdx.x - 256) * 16;
    const int row = tid >> 4, s = tid & 15;   // 16 lanes per logits row
    const float* src = logits + (size_t)(m0r + row) * F_;
    float4 a[8];
    #pragma unroll
    for (int j = 0; j < 8; ++j)
      a[j] = *(const float4*)(src + (s + 16 * j) * 4);
    float mx = fmaxf(fmaxf(a[0].x, a[0].y), fmaxf(a[0].z, a[0].w));
    #pragma unroll
    for (int j = 1; j < 8; ++j)
      mx = fmaxf(mx, fmaxf(fmaxf(a[j].x, a[j].y), fmaxf(a[j].z, a[j].w)));
    #pragma unroll
    for (int msk = 1; msk <= 8; msk <<= 1)
      mx = fmaxf(mx, __shfl_xor(mx, msk, 64));
    float sum = 0.0f;
    #pragma unroll
    for (int j = 0; j < 8; ++j) {
      a[j].x = __expf(a[j].x - mx); a[j].y = __expf(a[j].y - mx);
      a[j].z = __expf(a[j].z - mx); a[j].w = __expf(a[j].w - mx);
      sum += (a[j].x + a[j].y) + (a[j].z + a[j].w);
    }
    #pragma unroll
    for (int msk = 1; msk <= 8; msk <<= 1)
      sum += __shfl_xor(sum, msk, 64);
    float inv = 1.0f / sum;
    #pragma unroll
    for (int j = 0; j < 8; ++j) {
      int kc = 8 * j + (s >> 1), h = s & 1;
      uint2 u = make_uint2(pk2(a[j].x * inv, a[j].y * inv),
                           pk2(a[j].z * inv, a[j].w * inv));
      *(uint2*)(sm + (kc * 16 + (row ^ (kc & 15))) * 16 + h * 8) = u;
    }
    __syncthreads();
    const int w = tid >> 6, l = tid & 63;
    #pragma unroll
    for (int i = 0; i < 4; ++i) {
      int kc = w * 16 + i * 4 + (l >> 4);
      int slot = l & 15;
      int row2 = slot ^ (kc & 15);
      bf16x8 v = *(const bf16x8*)(sm + (kc * 16 + slot) * 16);
      *(bf16x8*)(wbF + ((size_t)kc * M_ + m0r + row2) * 8) = v;
    }
  }
}

// ---------------------------------------------------------------------------
// Round-10 GEMM: SINGLE-WAVE blocks, zero barriers, depth-4 prefetch.
// Round-9 post-mortem: 9 variants at 50-57us / 20-27% exclude LDS BW, cache
// locality, occupancy-alone, barrier-count, VMEM-instr-count. Surviving
// theory: multi-wave variants convoy on per-tile s_barrier pairs (barrier
// cost = max jitter of 4-8 waves on SIMDs shared with other blocks);
// barrier-free variants (R8/R9) had only depth-1 prefetch (~256-512cyc
// tolerance vs ~1000-1500cyc loaded latency) and <=2 waves/SIMD. This
// kernel hits the untried corner: 64-thread blocks (wave-synchronous, no
// s_barrier instructions at all), wave tile 64x64 (acc[2][2]=64 regs),
// operands direct global->register with a DEPTH-4 named ring (16 bf16x8 =
// 64 regs; all indices compile-time under full unroll, rule #20); ~170
// VGPR -> 3 waves/SIMD = 12 fully independent blocks/CU at 12 uncorrelated
// phases. Per k-step: 4 b128 loads (issued 4 steps = ~1200+ real cyc ahead)
// + 4 MFMA. Traffic cost of small tile: ~1GB L2 aggregate = 20-33 TB/s at
// 50-30us, inside the 34.5 TB/s ceiling.
// Grid 8192 flat, m-fast (128 consecutive blocks share a 64KB B strip).
// ---------------------------------------------------------------------------
__global__ __launch_bounds__(64, 3) void odst_mfma(
    const unsigned short* __restrict__ wbF,  // frag-major [KC][M] 16B cells
    const unsigned short* __restrict__ xbF,  // frag-major [KC][B] 16B cells
    const float* __restrict__ thr,           // [T][4]
    const float* __restrict__ leaf,          // [T][16]
    float* __restrict__ out) {               // [B][T]
  __shared__ __align__(16) float eb[64 * 18];    // epilogue only (4.5KB)

  const int lane = threadIdx.x;                // 1 wave
  const int col = lane & 31, hi = lane >> 5;
  const int bid = blockIdx.x;
  const int m0 = (bid & 127) * 64;             // m fast: neighbors share B
  const int n0 = (bid >> 7) * 64;

  // Per-lane fragment base: cell (kc = 2*ks + hi, row = m0/n0 + f*32 + col).
  // Lanes 0..31 read 32 consecutive 16B cells = one 512B segment.
  const unsigned short* pA = wbF + ((size_t)hi * M_ + m0 + col) * 8;
  const unsigned short* pB = xbF + ((size_t)hi * B_ + n0 + col) * 8;

  bf16x8 aR[4][2], bR[4][2];                   // depth-4 ring, 64 regs
  f32x16 acc[2][2] = {};

  auto LK = [&](int ks) {                      // 4 global b128 loads
    const int bf = ks & 3;
    #pragma unroll
    for (int f = 0; f < 2; ++f) {
      aR[bf][f] = *(const bf16x8*)(pA + ((size_t)(2 * ks) * M_ + f * 32) * 8);
      bR[bf][f] = *(const bf16x8*)(pB + ((size_t)(2 * ks) * B_ + f * 32) * 8);
    }
  };

  LK(0); LK(1); LK(2); LK(3);
  #pragma unroll
  for (int ks = 0; ks < 32; ++ks) {            // K = 32 steps x 16
    const int cb = ks & 3;                     // compile-time under unroll
    #pragma unroll
    for (int mf = 0; mf < 2; ++mf)
      #pragma unroll
      for (int nf = 0; nf < 2; ++nf)
        acc[mf][nf] = __builtin_amdgcn_mfma_f32_32x32x16_bf16(
            aR[cb][mf], bR[cb][nf], acc[mf][nf], 0, 0, 0);
    if (ks + 4 < 32) LK(ks + 4);               // refill the slot just freed
  }

  // ---- fused epilogue: C-layout n=col, d=reg&3, tree-in-frag=2g+hi ----
  const float inv_tau = 1.0f / TAU;
  const int t0 = m0 >> 2;                      // 16 trees per block
  #pragma unroll
  for (int mf = 0; mf < 2; ++mf) {
    #pragma unroll
    for (int g = 0; g < 4; ++g) {
      int tl = mf * 8 + 2 * g + hi;
      int tg = t0 + tl;
      float4 th  = *(const float4*)(thr + tg * 4);
      float4 lf0 = *(const float4*)(leaf + tg * 16);
      float4 lf1 = *(const float4*)(leaf + tg * 16 + 4);
      float4 lf2 = *(const float4*)(leaf + tg * 16 + 8);
      float4 lf3 = *(const float4*)(leaf + tg * 16 + 12);
      float c2x = th.x * inv_tau, c2y = th.y * inv_tau,
            c2z = th.z * inv_tau, c2w = th.w * inv_tau;
      #pragma unroll
      for (int nf = 0; nf < 2; ++nf) {
        float p0 = __builtin_amdgcn_rcpf(1.0f + __expf(fmaf(acc[mf][nf][g * 4 + 0], -inv_tau, c2x)));
        float p1 = __builtin_amdgcn_rcpf(1.0f + __expf(fmaf(acc[mf][nf][g * 4 + 1], -inv_tau, c2y)));
        float p2 = __builtin_amdgcn_rcpf(1.0f + __expf(fmaf(acc[mf][nf][g * 4 + 2], -inv_tau, c2z)));
        float p3 = __builtin_amdgcn_rcpf(1.0f + __expf(fmaf(acc[mf][nf][g * 4 + 3], -inv_tau, c2w)));
        float q0 = 1.0f - p0, q1 = 1.0f - p1, q2 = 1.0f - p2, q3 = 1.0f - p3;
        float A0 = lf0.x * q0 + lf0.y * p0;
        float A1 = lf0.z * q0 + lf0.w * p0;
        float A2 = lf1.x * q0 + lf1.y * p0;
        float A3 = lf1.z * q0 + lf1.w * p0;
        float A4 = lf2.x * q0 + lf2.y * p0;
        float A5 = lf2.z * q0 + lf2.w * p0;
        float A6 = lf3.x * q0 + lf3.y * p0;
        float A7 = lf3.z * q0 + lf3.w * p0;
        float B0 = A0 * q1 + A1 * p1;
        float B1 = A2 * q1 + A3 * p1;
        float B2 = A4 * q1 + A5 * p1;
        float B3 = A6 * q1 + A7 * p1;
        float C0 = B0 * q2 + B1 * p2;
        float C1 = B2 * q2 + B3 * p2;
        float o  = C0 * q3 + C1 * p3;
        int bl = nf * 32 + col;              // batch within block [0,64)
        eb[bl * 18 + tl] = o;                // stride 18: 8B-aligned rows
      }
    }
  }
  __syncthreads();                           // 1 wave: compiles to waitcnt

  // store: thread `lane` owns batch row `lane`: 16 floats -> 4 float4 stores
  {
    const float* p = eb + lane * 18;
    float* po = out + (size_t)(n0 + lane) * T_ + t0;
    #pragma unroll
    for (int s = 0; s < 4; ++s) {
      float2 v0 = *(const float2*)(p + s * 4);
      float2 v1 = *(const float2*)(p + s * 4 + 2);
      float4 v;
      v.x = v0.x; v.y = v0.y; v.z = v1.x; v.w = v1.y;
      *(float4*)(po + s * 4) = v;
    }
  }
}

extern "C" void kernel_launch(void* const* d_in, const int* in_sizes, int n_in,
                              void* d_out, int out_size, void* d_ws, size_t ws_size,
                              hipStream_t stream) {
  const float* x    = (const float*)d_in[0];  // (B, F)
  const float* fl   = (const float*)d_in[1];  // (T, D, F)
  const float* thr  = (const float*)d_in[2];  // (T, D)
  const float* leaf = (const float*)d_in[3];  // (T, 16)
  float* out = (float*)d_out;                 // (B, T)

  unsigned short* wbF = (unsigned short*)d_ws;                                  // 8 MB
  unsigned short* xbF = (unsigned short*)((char*)d_ws + (size_t)KC_ * M_ * 16); // 4 MB

  prep<<<dim3(768), dim3(256), 0, stream>>>(x, fl, xbF, wbF);
  odst_mfma<<<dim3(8192), dim3(64), 0, stream>>>(wbF, xbF, thr, leaf, out);
}

// Round 11
// 128.114 us; speedup vs baseline: 1.0743x; 1.0743x over previous
//
#include <hip/hip_runtime.h>
#include <stdint.h>

#define B_  4096
#define F_  512
#define T_  2048
#define D_  4
#define M_  (T_ * D_)   // 8192 GEMM-M (trees*dims)
#define KC_ (F_ / 8)    // 64 16-byte k-chunks per row
#define TAU 0.2018004745467103f

typedef __attribute__((ext_vector_type(8)))  short bf16x8;
typedef __attribute__((ext_vector_type(16))) float f32x16;

static __device__ __forceinline__ unsigned short f2bf(float f) {
  union { float f; uint32_t u; } v; v.f = f;
  uint32_t r = v.u + 0x7fffu + ((v.u >> 16) & 1u);  // RNE
  return (unsigned short)(r >> 16);
}
static __device__ __forceinline__ uint32_t pk2(float a, float b) {
  return ((uint32_t)f2bf(b) << 16) | f2bf(a);
}

// ---------------------------------------------------------------------------
// Prep v2 (verified round 5): fully-coalesced global IO via LDS transpose.
// ---------------------------------------------------------------------------
__global__ __launch_bounds__(256) void prep(
    const float* __restrict__ x, const float* __restrict__ logits,
    unsigned short* __restrict__ xbF, unsigned short* __restrict__ wbF) {
  __shared__ __align__(16) char sm[16384];
  const int tid = threadIdx.x;
  if (blockIdx.x < 256) {
    const int r0 = blockIdx.x * 16;
    const float4* x4 = (const float4*)x;
    #pragma unroll
    for (int p = 0; p < 8; ++p) {
      int idx = p * 256 + tid;
      int row = idx >> 7, col4 = idx & 127;
      int kc = col4 >> 1, half = col4 & 1;
      float4 f = x4[(size_t)(r0 + row) * 128 + col4];
      uint2 u = make_uint2(pk2(f.x, f.y), pk2(f.z, f.w));
      *(uint2*)(sm + (kc * 16 + (row ^ (kc & 15))) * 16 + half * 8) = u;
    }
    __syncthreads();
    const int w = tid >> 6, l = tid & 63;
    #pragma unroll
    for (int i = 0; i < 4; ++i) {
      int kc = w * 16 + i * 4 + (l >> 4);
      int slot = l & 15;
      int row = slot ^ (kc & 15);
      bf16x8 v = *(const bf16x8*)(sm + (kc * 16 + slot) * 16);
      *(bf16x8*)(xbF + ((size_t)kc * B_ + r0 + row) * 8) = v;
    }
  } else {
    const int m0r = (blockIdx.x - 256) * 16;
    const int row = tid >> 4, s = tid & 15;   // 16 lanes per logits row
    const float* src = logits + (size_t)(m0r + row) * F_;
    float4 a[8];
    #pragma unroll
    for (int j = 0; j < 8; ++j)
      a[j] = *(const float4*)(src + (s + 16 * j) * 4);
    float mx = fmaxf(fmaxf(a[0].x, a[0].y), fmaxf(a[0].z, a[0].w));
    #pragma unroll
    for (int j = 1; j < 8; ++j)
      mx = fmaxf(mx, fmaxf(fmaxf(a[j].x, a[j].y), fmaxf(a[j].z, a[j].w)));
    #pragma unroll
    for (int msk = 1; msk <= 8; msk <<= 1)
      mx = fmaxf(mx, __shfl_xor(mx, msk, 64));
    float sum = 0.0f;
    #pragma unroll
    for (int j = 0; j < 8; ++j) {
      a[j].x = __expf(a[j].x - mx); a[j].y = __expf(a[j].y - mx);
      a[j].z = __expf(a[j].z - mx); a[j].w = __expf(a[j].w - mx);
      sum += (a[j].x + a[j].y) + (a[j].z + a[j].w);
    }
    #pragma unroll
    for (int msk = 1; msk <= 8; msk <<= 1)
      sum += __shfl_xor(sum, msk, 64);
    float inv = 1.0f / sum;
    #pragma unroll
    for (int j = 0; j < 8; ++j) {
      int kc = 8 * j + (s >> 1), h = s & 1;
      uint2 u = make_uint2(pk2(a[j].x * inv, a[j].y * inv),
                           pk2(a[j].z * inv, a[j].w * inv));
      *(uint2*)(sm + (kc * 16 + (row ^ (kc & 15))) * 16 + h * 8) = u;
    }
    __syncthreads();
    const int w = tid >> 6, l = tid & 63;
    #pragma unroll
    for (int i = 0; i < 4; ++i) {
      int kc = w * 16 + i * 4 + (l >> 4);
      int slot = l & 15;
      int row2 = slot ^ (kc & 15);
      bf16x8 v = *(const bf16x8*)(sm + (kc * 16 + slot) * 16);
      *(bf16x8*)(wbF + ((size_t)kc * M_ + m0r + row2) * 8) = v;
    }
  }
}

// ---------------------------------------------------------------------------
// Round-11 GEMM: R6 byte-identical, single variable changed: occupancy cap
// 3 -> 4 blocks/CU (launch_bounds(256,4); R6's measured VGPR=64 fits the
// 128-reg cap; LDS 32KB allows 5).
// Model under test (round-10 post-mortem): block wall = sum over K-tiles of
// the serial per-tile latency chain (barrier reconvergence + loaded LDS
// latency + MFMA), which multi-wave TLP does NOT compress; throughput
// scales with SEQUENTIAL BLOCK ROUNDS. Grid 2048: at 3/CU = 2.67 rounds,
// at 4/CU = exactly 2 rounds -> predicted odst 50 -> ~39-43us.
// If it ties ~50us/27% again, the ceiling is structure-independent (7th
// tie) and the session finalizes on the best-total kernel.
// Structure (R6): block 128x128, 4 waves 2x2, wave 64x64 (acc[2][2]=64
// regs), BK=32 double-buffered = 32KB LDS, counted VMCNT(4) (loads issued
// one full tile-period earlier), frag-major [kc][128 row] 16B cells
// (conflict-free b128 reads + linear 1KB global_load_lds chunks).
// Grid 64(m) x 32(n), m fast -> consecutive blocks share the B strip.
// ---------------------------------------------------------------------------
#define SBAR()  do { __builtin_amdgcn_sched_barrier(0); \
                     __builtin_amdgcn_s_barrier(); \
                     __builtin_amdgcn_sched_barrier(0); } while (0)
#define LGKM0() do { asm volatile("s_waitcnt lgkmcnt(0)" ::: "memory"); \
                     __builtin_amdgcn_sched_barrier(0); } while (0)
#define VMCNT(n) do { asm volatile("s_waitcnt vmcnt(" #n ")" ::: "memory"); \
                      __builtin_amdgcn_sched_barrier(0); } while (0)

__global__ __launch_bounds__(256, 4) void odst_mfma(
    const unsigned short* __restrict__ wbF,  // frag-major [KC][M] 16B cells
    const unsigned short* __restrict__ xbF,  // frag-major [KC][B] 16B cells
    const float* __restrict__ thr,           // [T][4]
    const float* __restrict__ leaf,          // [T][16]
    float* __restrict__ out) {               // [B][T]
  __shared__ __align__(16) char smem[32768];

  const int tid  = threadIdx.x;
  const int lane = tid & 63, wid = tid >> 6;   // 4 waves
  const int wm = wid >> 1, wn = wid & 1;       // 2 (m) x 2 (n)
  const int col = lane & 31, hi = lane >> 5;
  const int m0 = blockIdx.x * 128;             // m fast: neighbors share B
  const int n0 = blockIdx.y * 128;

  // wave `wid` stages kc slot `wid` of each BK=32 tile (global kc = t*4+wid)
  const unsigned short* gA = wbF + ((size_t)wid * M_ + m0 + lane) * 8;
  const unsigned short* gB = xbF + ((size_t)wid * B_ + n0 + lane) * 8;

  auto stage = [&](int t) {                    // 4 x 1KB wave-chunks
    char* base = smem + (t & 1) * 16384;
    #pragma unroll
    for (int j = 0; j < 2; ++j) {
      __builtin_amdgcn_global_load_lds(
          (const __attribute__((address_space(1))) uint32_t*)(
              gA + ((size_t)t * 4 * M_ + j * 64) * 8),
          (__attribute__((address_space(3))) uint32_t*)(
              base + (wid * 128 + j * 64) * 16),
          16, 0, 0);
      __builtin_amdgcn_global_load_lds(
          (const __attribute__((address_space(1))) uint32_t*)(
              gB + ((size_t)t * 4 * B_ + j * 64) * 8),
          (__attribute__((address_space(3))) uint32_t*)(
              base + 8192 + (wid * 128 + j * 64) * 16),
          16, 0, 0);
    }
  };

  f32x16 acc[2][2] = {};

  stage(0);

  #pragma unroll
  for (int t = 0; t < 16; ++t) {               // K = 16 tiles x BK=32
    if (t < 15) { stage(t + 1); VMCNT(4); }    // tile t resident (4 in flight)
    else        { VMCNT(0); }
    SBAR();                                    // all waves' stages visible
    const char* base = smem + (t & 1) * 16384;
    bf16x8 a[2][2], b[2][2];
    #pragma unroll
    for (int ks = 0; ks < 2; ++ks) {
      #pragma unroll
      for (int mf = 0; mf < 2; ++mf)
        a[mf][ks] = *(const bf16x8*)(base +
            ((2 * ks + hi) * 128 + wm * 64 + mf * 32 + col) * 16);
      #pragma unroll
      for (int nf = 0; nf < 2; ++nf)
        b[nf][ks] = *(const bf16x8*)(base + 8192 +
            ((2 * ks + hi) * 128 + wn * 64 + nf * 32 + col) * 16);
    }
    LGKM0();
    #pragma unroll
    for (int ks = 0; ks < 2; ++ks)
      #pragma unroll
      for (int mf = 0; mf < 2; ++mf)
        #pragma unroll
        for (int nf = 0; nf < 2; ++nf)
          acc[mf][nf] = __builtin_amdgcn_mfma_f32_32x32x16_bf16(
              a[mf][ks], b[nf][ks], acc[mf][nf], 0, 0, 0);
    SBAR();                                    // reads done before overwrite
  }

  __syncthreads();  // LDS reusable for epilogue

  // ---- fused epilogue: C-layout n=col, d=reg&3, tree-in-frag=2g+hi ----
  float* eb = (float*)smem;                  // [128 batch][34] floats
  const float inv_tau = 1.0f / TAU;
  const int t0 = m0 >> 2;                    // 32 trees per block
  #pragma unroll
  for (int mf = 0; mf < 2; ++mf) {
    #pragma unroll
    for (int g = 0; g < 4; ++g) {
      int tl = wm * 16 + mf * 8 + 2 * g + hi;
      int tg = t0 + tl;
      float4 th  = *(const float4*)(thr + tg * 4);
      float4 lf0 = *(const float4*)(leaf + tg * 16);
      float4 lf1 = *(const float4*)(leaf + tg * 16 + 4);
      float4 lf2 = *(const float4*)(leaf + tg * 16 + 8);
      float4 lf3 = *(const float4*)(leaf + tg * 16 + 12);
      float c2x = th.x * inv_tau, c2y = th.y * inv_tau,
            c2z = th.z * inv_tau, c2w = th.w * inv_tau;
      #pragma unroll
      for (int nf = 0; nf < 2; ++nf) {
        float p0 = __builtin_amdgcn_rcpf(1.0f + __expf(fmaf(acc[mf][nf][g * 4 + 0], -inv_tau, c2x)));
        float p1 = __builtin_amdgcn_rcpf(1.0f + __expf(fmaf(acc[mf][nf][g * 4 + 1], -inv_tau, c2y)));
        float p2 = __builtin_amdgcn_rcpf(1.0f + __expf(fmaf(acc[mf][nf][g * 4 + 2], -inv_tau, c2z)));
        float p3 = __builtin_amdgcn_rcpf(1.0f + __expf(fmaf(acc[mf][nf][g * 4 + 3], -inv_tau, c2w)));
        float q0 = 1.0f - p0, q1 = 1.0f - p1, q2 = 1.0f - p2, q3 = 1.0f - p3;
        float A0 = lf0.x * q0 + lf0.y * p0;
        float A1 = lf0.z * q0 + lf0.w * p0;
        float A2 = lf1.x * q0 + lf1.y * p0;
        float A3 = lf1.z * q0 + lf1.w * p0;
        float A4 = lf2.x * q0 + lf2.y * p0;
        float A5 = lf2.z * q0 + lf2.w * p0;
        float A6 = lf3.x * q0 + lf3.y * p0;
        float A7 = lf3.z * q0 + lf3.w * p0;
        float B0 = A0 * q1 + A1 * p1;
        float B1 = A2 * q1 + A3 * p1;
        float B2 = A4 * q1 + A5 * p1;
        float B3 = A6 * q1 + A7 * p1;
        float C0 = B0 * q2 + B1 * p2;
        float C1 = B2 * q2 + B3 * p2;
        float o  = C0 * q3 + C1 * p3;
        int bl = wn * 64 + nf * 32 + col;    // batch within block [0,128)
        eb[bl * 34 + tl] = o;                // stride 34: 2-way (free)
      }
    }
  }
  __syncthreads();

  // coalesced store: 128 batch rows x 32 trees, float4 per thread-slot
  #pragma unroll
  for (int pass = 0; pass < 4; ++pass) {
    int row = pass * 32 + (tid >> 3);
    int s   = tid & 7;
    const float* p = eb + row * 34 + s * 4;
    float2 v0 = *(const float2*)p;
    float2 v1 = *(const float2*)(p + 2);
    float4 v;
    v.x = v0.x; v.y = v0.y; v.z = v1.x; v.w = v1.y;
    *(float4*)(out + (size_t)(n0 + row) * T_ + t0 + s * 4) = v;
  }
}

extern "C" void kernel_launch(void* const* d_in, const int* in_sizes, int n_in,
                              void* d_out, int out_size, void* d_ws, size_t ws_size,
                              hipStream_t stream) {
  const float* x    = (const float*)d_in[0];  // (B, F)
  const float* fl   = (const float*)d_in[1];  // (T, D, F)
  const float* thr  = (const float*)d_in[2];  // (T, D)
  const float* leaf = (const float*)d_in[3];  // (T, 16)
  float* out = (float*)d_out;                 // (B, T)

  unsigned short* wbF = (unsigned short*)d_ws;                                  // 8 MB
  unsigned short* xbF = (unsigned short*)((char*)d_ws + (size_t)KC_ * M_ * 16); // 4 MB

  prep<<<dim3(768), dim3(256), 0, stream>>>(x, fl, xbF, wbF);
  odst_mfma<<<dim3(M_ / 128, B_ / 128), dim3(256), 0, stream>>>(wbF, xbF, thr, leaf, out);
}